// Round 8
// baseline (104.060 us; speedup 1.0000x reference)
//
#include <hip/hip_runtime.h>

// VectorQuantizer: B=32,D=64,H=64,W=64 -> N=131072 px; K=512 codes.
// out[0] = 1.25*mean((E[idx]-z)^2); out[1..] = Zq as [B,D,H,W].
// R7 = R6 (barrier-free; fragment-major E16s -> fully-coalesced B loads;
// depth-4 B-prefetch ring; cooperative gather) but each wave owns 64
// CONTIGUOUS px (two 32-px MFMA tiles sharing one staging wait and one
// B-stream) -> half the latency chains, half the total L2 B-traffic.
// Zq parked as bf16 in zqT[64][66] (E in +-1/512 => bf16 err ~4e-5 << 0.025)
// so stores are full 256-B segments (lane=px), nontemporal to spare L2.
// dist = en2 + (-2z).e via MFMA C operand, in (1,3) => raw uint bits are
// order-monotone; low 9 bits carry code idx. Loss -> cells -> tiny reducer.

typedef __bf16 bf16x8 __attribute__((ext_vector_type(8)));
typedef float  f32x4  __attribute__((ext_vector_type(4)));
typedef int    i32x4  __attribute__((ext_vector_type(4)));

#define LOSS_SCALE (1.25f / 8388608.f)   // 1.25 / (N*D)

// ---- prep: E fp32 -> E16s (fragment-major bf16) + en2s ---------------------
// E16s (bf16 units): [((ct*2 + half)*64 + lane) * 8 + j]
//   lane=(q=lane>>4, m=lane&15): code c = ct*16+m, dim = half*32 + q*8 + j
// en2s[ct*64 + lane] = |E[ct*16 + (lane&15)]|^2 + 2
__global__ __launch_bounds__(256) void vq_prep(const float* __restrict__ E,
                                               __bf16* __restrict__ E16s,
                                               float* __restrict__ en2s) {
  int tau = blockIdx.x * 256 + threadIdx.x;        // 4096 threads
  int lane = tau & 63, half = (tau >> 6) & 1, ct = tau >> 7;
  int m = lane & 15, q = lane >> 4;
  int c = ct * 16 + m;
  const float* src = E + c * 64 + half * 32 + q * 8;
  float4 s0 = *(const float4*)src;
  float4 s1 = *(const float4*)(src + 4);
  bf16x8 b;
  b[0] = (__bf16)s0.x; b[1] = (__bf16)s0.y; b[2] = (__bf16)s0.z; b[3] = (__bf16)s0.w;
  b[4] = (__bf16)s1.x; b[5] = (__bf16)s1.y; b[6] = (__bf16)s1.z; b[7] = (__bf16)s1.w;
  *(bf16x8*)(E16s + tau * 8) = b;
  if (half == 0) {                                 // redundant x16 but tiny
    const float4* row = (const float4*)(E + c * 64);
    float ss = 0.f;
    #pragma unroll
    for (int i = 0; i < 16; ++i) {
      float4 v = row[i];
      ss += v.x * v.x + v.y * v.y + v.z * v.z + v.w * v.w;
    }
    en2s[ct * 64 + lane] = ss + 2.0f;
  }
}

#define ARGMIN(KK, RV) { unsigned key_ = (__float_as_uint(RV) & 0xFFFFFE00u) | cvec; \
                         if (key_ < KK) KK = key_; }
#define MERGE16(KK) { unsigned o_; \
    o_ = __shfl_xor(KK, 1); if (o_ < KK) KK = o_; \
    o_ = __shfl_xor(KK, 2); if (o_ < KK) KK = o_; \
    o_ = __shfl_xor(KK, 4); if (o_ < KK) KK = o_; \
    o_ = __shfl_xor(KK, 8); if (o_ < KK) KK = o_; }

__global__ __launch_bounds__(256, 2) void vq_main(const float* __restrict__ in,
                                                  const float* __restrict__ E,
                                                  const __bf16* __restrict__ E16s,
                                                  const float* __restrict__ en2s,
                                                  float* __restrict__ out,
                                                  float* __restrict__ cells) {
  // per-wave arena: staging (2 x 32px x 72 bf16) OR bf16 zqT[64][66]
  struct Arena { union { __bf16 z[2][2304]; __bf16 zq[64 * 66]; } u; };
  __shared__ Arena ar[4];
  __shared__ int idxl[4][64];

  const int t = threadIdx.x, lane = t & 63, w = t >> 6;
  const int q = lane >> 4, m = lane & 15;
  const int W = blockIdx.x * 4 + w;                 // wave 0..2047 (64 px)
  const int base = (W >> 6) * 262144 + ((W & 63) << 6);

  // ---- stage both 32-px tiles: lane loads float2 (px 2m,2m+1 / +32) --------
  float zn = 0.f;
  {
    float2 L0[16], L1[16];
    const float* p0 = in + base + (q * 16) * 4096 + 2 * m;
    #pragma unroll
    for (int j = 0; j < 16; ++j) L0[j] = *(const float2*)(p0 + j * 4096);
    #pragma unroll
    for (int j = 0; j < 16; ++j) L1[j] = *(const float2*)(p0 + 32 + j * 4096);
    #pragma unroll
    for (int tt = 0; tt < 2; ++tt) {
      float2* L = tt ? L1 : L0;
      bf16x8 c00, c01, c10, c11;
      #pragma unroll
      for (int j = 0; j < 8; ++j) {
        c00[j] = (__bf16)(-2.f * L[j].x);
        c10[j] = (__bf16)(-2.f * L[j].y);
        c01[j] = (__bf16)(-2.f * L[j + 8].x);
        c11[j] = (__bf16)(-2.f * L[j + 8].y);
      }
      #pragma unroll
      for (int j = 0; j < 16; ++j) zn += L[j].x * L[j].x + L[j].y * L[j].y;
      __bf16* r0 = &ar[w].u.z[tt][(2 * m) * 72 + q * 16];
      __bf16* r1 = &ar[w].u.z[tt][(2 * m + 1) * 72 + q * 16];
      *(bf16x8*)r0 = c00; *(bf16x8*)(r0 + 8) = c01;
      *(bf16x8*)r1 = c10; *(bf16x8*)(r1 + 8) = c11;
    }
  }
  __threadfence_block();                  // wave-local LDS visibility

  // ---- A fragments: tile tt, px = pt*16+m, k-halves q*8 / 32+q*8 -----------
  bf16x8 A[2][2][2];                      // [tile][pt][half]
  #pragma unroll
  for (int tt = 0; tt < 2; ++tt)
    #pragma unroll
    for (int pt = 0; pt < 2; ++pt) {
      A[tt][pt][0] = *(const bf16x8*)&ar[w].u.z[tt][(pt * 16 + m) * 72 + q * 8];
      A[tt][pt][1] = *(const bf16x8*)&ar[w].u.z[tt][(pt * 16 + m) * 72 + 32 + q * 8];
    }

  unsigned k000 = ~0u, k001 = ~0u, k002 = ~0u, k003 = ~0u;
  unsigned k010 = ~0u, k011 = ~0u, k012 = ~0u, k013 = ~0u;
  unsigned k100 = ~0u, k101 = ~0u, k102 = ~0u, k103 = ~0u;
  unsigned k110 = ~0u, k111 = ~0u, k112 = ~0u, k113 = ~0u;

  // ---- stream all 512 codes: 32 tiles, depth-4 prefetch ring ---------------
  const __bf16* Eb = E16s + lane * 8;     // + ct*1024 (+512 for B1)
  bf16x8 P0[4], P1[4];
  float  PE[4];
  #pragma unroll
  for (int i = 0; i < 4; ++i) {
    P0[i] = *(const bf16x8*)(Eb + i * 1024);
    P1[i] = *(const bf16x8*)(Eb + i * 1024 + 512);
    PE[i] = en2s[i * 64 + lane];
  }
  #pragma unroll
  for (int ct = 0; ct < 32; ++ct) {
    const int s = ct & 3;
    bf16x8 B0 = P0[s], B1 = P1[s];
    float  en = PE[s];
    {                                     // refill slot with tile ct+4 (clamped)
      int nt = ct + 4; nt = nt > 31 ? 31 : nt;
      P0[s] = *(const bf16x8*)(Eb + nt * 1024);
      P1[s] = *(const bf16x8*)(Eb + nt * 1024 + 512);
      PE[s] = en2s[nt * 64 + lane];
    }
    f32x4 einit = {en, en, en, en};
    const unsigned cvec = (unsigned)(ct * 16 + m);
    f32x4 a00 = __builtin_amdgcn_mfma_f32_16x16x32_bf16(A[0][0][0], B0, einit, 0, 0, 0);
    a00 = __builtin_amdgcn_mfma_f32_16x16x32_bf16(A[0][0][1], B1, a00, 0, 0, 0);
    f32x4 a01 = __builtin_amdgcn_mfma_f32_16x16x32_bf16(A[0][1][0], B0, einit, 0, 0, 0);
    a01 = __builtin_amdgcn_mfma_f32_16x16x32_bf16(A[0][1][1], B1, a01, 0, 0, 0);
    f32x4 a10 = __builtin_amdgcn_mfma_f32_16x16x32_bf16(A[1][0][0], B0, einit, 0, 0, 0);
    a10 = __builtin_amdgcn_mfma_f32_16x16x32_bf16(A[1][0][1], B1, a10, 0, 0, 0);
    f32x4 a11 = __builtin_amdgcn_mfma_f32_16x16x32_bf16(A[1][1][0], B0, einit, 0, 0, 0);
    a11 = __builtin_amdgcn_mfma_f32_16x16x32_bf16(A[1][1][1], B1, a11, 0, 0, 0);
    ARGMIN(k000, a00[0]) ARGMIN(k001, a00[1]) ARGMIN(k002, a00[2]) ARGMIN(k003, a00[3])
    ARGMIN(k010, a01[0]) ARGMIN(k011, a01[1]) ARGMIN(k012, a01[2]) ARGMIN(k013, a01[3])
    ARGMIN(k100, a10[0]) ARGMIN(k101, a10[1]) ARGMIN(k102, a10[2]) ARGMIN(k103, a10[3])
    ARGMIN(k110, a11[0]) ARGMIN(k111, a11[1]) ARGMIN(k112, a11[2]) ARGMIN(k113, a11[3])
  }

  // ---- merge across the 16 code-column lanes -------------------------------
  MERGE16(k000) MERGE16(k001) MERGE16(k002) MERGE16(k003)
  MERGE16(k010) MERGE16(k011) MERGE16(k012) MERGE16(k013)
  MERGE16(k100) MERGE16(k101) MERGE16(k102) MERGE16(k103)
  MERGE16(k110) MERGE16(k111) MERGE16(k112) MERGE16(k113)

  if (m == 0) {                 // publish winners: px = tt*32 + pt*16 + q*4 + r
    i32x4 v;
    v[0] = (int)(k000 & 511u); v[1] = (int)(k001 & 511u);
    v[2] = (int)(k002 & 511u); v[3] = (int)(k003 & 511u);
    *(i32x4*)&idxl[w][q * 4] = v;
    v[0] = (int)(k010 & 511u); v[1] = (int)(k011 & 511u);
    v[2] = (int)(k012 & 511u); v[3] = (int)(k013 & 511u);
    *(i32x4*)&idxl[w][16 + q * 4] = v;
    v[0] = (int)(k100 & 511u); v[1] = (int)(k101 & 511u);
    v[2] = (int)(k102 & 511u); v[3] = (int)(k103 & 511u);
    *(i32x4*)&idxl[w][32 + q * 4] = v;
    v[0] = (int)(k110 & 511u); v[1] = (int)(k111 & 511u);
    v[2] = (int)(k112 & 511u); v[3] = (int)(k113 & 511u);
    *(i32x4*)&idxl[w][48 + q * 4] = v;
  }

  // ---- loss partial --------------------------------------------------------
  float ll = zn;
  if (m == 0) {
    ll += (__uint_as_float(k000) - 2.f) + (__uint_as_float(k001) - 2.f)
        + (__uint_as_float(k002) - 2.f) + (__uint_as_float(k003) - 2.f)
        + (__uint_as_float(k010) - 2.f) + (__uint_as_float(k011) - 2.f)
        + (__uint_as_float(k012) - 2.f) + (__uint_as_float(k013) - 2.f)
        + (__uint_as_float(k100) - 2.f) + (__uint_as_float(k101) - 2.f)
        + (__uint_as_float(k102) - 2.f) + (__uint_as_float(k103) - 2.f)
        + (__uint_as_float(k110) - 2.f) + (__uint_as_float(k111) - 2.f)
        + (__uint_as_float(k112) - 2.f) + (__uint_as_float(k113) - 2.f);
  }
  #pragma unroll
  for (int off = 1; off < 64; off <<= 1) ll += __shfl_xor(ll, off);
  if (lane == 0) cells[W] = ll;

  __threadfence_block();                  // idxl visible within the wave

  // ---- cooperative gather into bf16 zqT[64][66]: 4 rows per step -----------
  // step j: px p = j*4 + q; lane fetches dims 4m..4m+3 of winner row
  __bf16* zqT = ar[w].u.zq;
  #pragma unroll
  for (int j = 0; j < 16; ++j) {
    int p = j * 4 + q;
    int row = idxl[w][p];
    float4 v = *(const float4*)(E + row * 64 + m * 4);
    zqT[(4 * m + 0) * 66 + p] = (__bf16)v.x;
    zqT[(4 * m + 1) * 66 + p] = (__bf16)v.y;
    zqT[(4 * m + 2) * 66 + p] = (__bf16)v.z;
    zqT[(4 * m + 3) * 66 + p] = (__bf16)v.w;
  }
  __threadfence_block();

  // ---- store: lane = px, full 256-B segment per d, nontemporal -------------
  {
    float* op = out + 1 + base + lane;
    #pragma unroll
    for (int d = 0; d < 64; ++d) {
      float v = (float)zqT[d * 66 + lane];
      __builtin_nontemporal_store(v, op + d * 4096);
    }
  }
}

// ---- tiny reduce: sum 2048 wave partials -> out[0] -------------------------
__global__ __launch_bounds__(256) void vq_loss(const float* __restrict__ cells,
                                               float* __restrict__ out) {
  __shared__ float wsum[4];
  int t = threadIdx.x;
  const float4* c4 = (const float4*)cells;         // 512 float4
  float s = 0.f;
  #pragma unroll
  for (int j = 0; j < 2; ++j) {
    float4 v = c4[t + 256 * j];
    s += v.x + v.y + v.z + v.w;
  }
  #pragma unroll
  for (int off = 1; off < 64; off <<= 1) s += __shfl_xor(s, off);
  if ((t & 63) == 0) wsum[t >> 6] = s;
  __syncthreads();
  if (t == 0) out[0] = (wsum[0] + wsum[1] + wsum[2] + wsum[3]) * LOSS_SCALE;
}

extern "C" void kernel_launch(void* const* d_in, const int* in_sizes, int n_in,
                              void* d_out, int out_size, void* d_ws, size_t ws_size,
                              hipStream_t stream) {
  (void)in_sizes; (void)n_in; (void)out_size; (void)ws_size;
  const float* in = (const float*)d_in[0];   // [32,64,64,64]
  const float* E  = (const float*)d_in[1];   // [512,64]
  float* out = (float*)d_out;                // [1 + 8388608]
  __bf16* E16s  = (__bf16*)d_ws;                       // 64 KiB
  float*  en2s  = (float*)((char*)d_ws + 65536);       // 8 KiB
  float*  cells = (float*)((char*)d_ws + 73728);       // 8 KiB

  vq_prep<<<16, 256, 0, stream>>>(E, E16s, en2s);
  vq_main<<<512, 256, 0, stream>>>(in, E, E16s, en2s, out, cells);
  vq_loss<<<1, 256, 0, stream>>>(cells, out);
}